// Round 5
// baseline (342.026 us; speedup 1.0000x reference)
//
#include <hip/hip_runtime.h>
#include <hip/hip_bf16.h>
#include <math.h>

// Problem constants
#define TT 48
#define NSEQ (16*2048)
#define NP 12

// MFMA fragment types (gfx950: mfma_f32_16x16x32_bf16)
typedef __bf16 bf16x8 __attribute__((ext_vector_type(8)));
typedef float  f32x4  __attribute__((ext_vector_type(4)));

// ws layout.
// bf16 region (ws viewed as __bf16*), all B-frag swizzled [((k>>3)*N + n)*8 + (k&7)]:
//   [0)      WccB  96x64   (folded W_in @ W_conv)
//   [6144)   MqkB  64x64   (0.125 * Wq @ Wk^T, k-index = d, n-index = c)
//   [10240)  WvB   64x64
//   [18432)  W1B   64x256
//   [34816)  W2B   256x128   -> ends 67584 bf16 == float idx 33792
// float region (ws viewed as float*):
//   [33792)  btot 64   (bc0+bc1+bc2+b_conv)
//   [33856)  bc0  64
//   [33920)  bc2  64
//   [33984)  kv0  64   (0.125 * Wk @ bq)
//   [34048)  ctx  32768*64
#define OFF_WCC 0
#define OFF_MQK 6144
#define OFF_WV  10240
#define OFF_W1  18432
#define OFF_W2  34816
#define WS_BTOT 33792
#define WS_BC0  33856
#define WS_BC2  33920
#define WS_KV0  33984
#define WS_CTX  34048

__device__ __forceinline__ f32x4 zero4() {
  f32x4 z; z[0] = 0.f; z[1] = 0.f; z[2] = 0.f; z[3] = 0.f; return z;
}

union PackU { bf16x8 v; __hip_bfloat162 h[4]; };
union Pack4 { unsigned long long u; __hip_bfloat162 h[2]; };

// packed fp32x8 -> bf16x8 conversion (v_cvt_pk_bf16_f32)
__device__ __forceinline__ bf16x8 pack8(float4 a, float4 b) {
  PackU u;
  u.h[0] = __float22bfloat162_rn(make_float2(a.x, a.y));
  u.h[1] = __float22bfloat162_rn(make_float2(a.z, a.w));
  u.h[2] = __float22bfloat162_rn(make_float2(b.x, b.y));
  u.h[3] = __float22bfloat162_rn(make_float2(b.z, b.w));
  return u.v;
}

// packed fp32x4 -> 4x bf16 (8B) conversion
__device__ __forceinline__ unsigned long long pack4(float4 a) {
  Pack4 u;
  u.h[0] = __float22bfloat162_rn(make_float2(a.x, a.y));
  u.h[1] = __float22bfloat162_rn(make_float2(a.z, a.w));
  return u.u;
}

// ---------------------------------------------------------------------------
// Prep: fold W_in into conv weights; precompute M_qk = 0.125*Wq@Wk^T and
// kv0 = 0.125*Wk@bq (softmax shift-invariance kills all other q/k terms);
// convert all GEMM weights to bf16 in B-frag-swizzled order.
// ---------------------------------------------------------------------------
__global__ __launch_bounds__(256) void prep_kernel(
    const float* __restrict__ W_in, const float* __restrict__ b_in,
    const float* __restrict__ W_conv, const float* __restrict__ b_conv,
    const float* __restrict__ Wk, const float* __restrict__ Wv,
    const float* __restrict__ Wq, const float* __restrict__ bq,
    const float* __restrict__ W1, const float* __restrict__ W2,
    float* __restrict__ ws)
{
  __bf16* wsb = (__bf16*)ws;
  const int tid = threadIdx.x;
  const int bid = blockIdx.x;
  if (bid < 24) {                       // WccB: fold W_in into W_conv
    int gid = bid * 256 + tid;          // 0..6143
    int kk = gid >> 6;                  // 0..95
    int c  = gid & 63;
    int dt = kk >> 5;
    int e  = kk & 31;
    const float* wrow = W_in + e * 64;
    const float* wc   = W_conv + dt * 4096 + c;
    float acc = 0.f;
    #pragma unroll 8
    for (int c0 = 0; c0 < 64; ++c0)
      acc = fmaf(wrow[c0], wc[c0 * 64], acc);
    wsb[OFF_WCC + ((kk >> 3) * 64 + c) * 8 + (kk & 7)] = (__bf16)acc;
  } else if (bid < 40) {                // MqkB = 0.125 * Wq @ Wk^T  (k=d, n=c)
    int gid = (bid - 24) * 256 + tid;   // 0..4095
    int d = gid >> 6, c = gid & 63;
    const float* qr = Wq + d * 64;
    const float* kr = Wk + c * 64;
    float acc = 0.f;
    #pragma unroll 8
    for (int j = 0; j < 64; ++j) acc = fmaf(qr[j], kr[j], acc);
    wsb[OFF_MQK + ((d >> 3) * 64 + c) * 8 + (d & 7)] = (__bf16)(0.125f * acc);
  } else if (bid < 56) {                // WvB
    int gid = (bid - 40) * 256 + tid;
    int kk = gid >> 6, c = gid & 63;
    wsb[OFF_WV + ((kk >> 3) * 64 + c) * 8 + (kk & 7)] = (__bf16)Wv[kk * 64 + c];
  } else if (bid < 120) {               // W1B (64x256)
    int gid = (bid - 56) * 256 + tid;   // 0..16383
    int kk = gid >> 8, n = gid & 255;
    wsb[OFF_W1 + ((kk >> 3) * 256 + n) * 8 + (kk & 7)] = (__bf16)W1[kk * 256 + n];
  } else if (bid < 248) {               // W2B (256x128)
    int gid = (bid - 120) * 256 + tid;  // 0..32767
    int kk = gid >> 7, n = gid & 127;
    wsb[OFF_W2 + ((kk >> 3) * 128 + n) * 8 + (kk & 7)] = (__bf16)W2[kk * 128 + n];
  } else if (tid < 64) {                // biases + kv0
    int c = tid;
    float s[3];
    for (int dt = 0; dt < 3; ++dt) {
      const float* wc = W_conv + dt * 4096 + c;
      float a = 0.f;
      for (int c0 = 0; c0 < 64; ++c0) a = fmaf(b_in[c0], wc[c0 * 64], a);
      s[dt] = a;
    }
    ws[WS_BC0 + c]  = s[0];
    ws[WS_BC2 + c]  = s[2];
    ws[WS_BTOT + c] = s[0] + s[1] + s[2] + b_conv[c];
    float a = 0.f;
    const float* kr = Wk + c * 64;
    for (int j = 0; j < 64; ++j) a = fmaf(kr[j], bq[j], a);
    ws[WS_KV0 + c] = 0.125f * a;
  }
}

// ---------------------------------------------------------------------------
// Attention kernel: ONE WAVE = TWO SEQUENCES, block = 128 threads (4 seqs).
// No __syncthreads (each wave owns its 2 seqs' LDS).  Algebraically reduced
// attention (unchanged math): scores[t] = h1[t].w, w = Mqk-GEMV(h1[47])+kv0;
// softmax via 4 cross-quad shuffles; ctx = sum_t p[t]*V[t] + bv.
// THIS ROUND (2x ILP + weight sharing + LDS union):
//  - every dependent chain now has an independent twin (2 seqs interleaved),
//    halving exposed latency per seq;
//  - all weight B-frags (WccB/MqkB/WvB) loaded ONCE per wave, shared by both
//    seqs -> half the serialized L2 round trips per seq;
//  - both conv halves' accs live at once (96 f32) -> ALL x-tile reads finish
//    before h1 is written -> x-tile legally overlays h1 (LDS 28.2KB/blk,
//    5 blocks/CU, 20 seq-streams/CU vs round-4's 14);
//  - __launch_bounds__(128,2) caps VGPR at 256 so the ~160-reg live state
//    cannot spill (round-3 lesson: spill shows as WRITE_SIZE 287MB).
// ---------------------------------------------------------------------------
__global__ __launch_bounds__(128, 2) void attn_kernel(
    const float* __restrict__ x, const float* __restrict__ bv,
    const float* __restrict__ ws, float* __restrict__ ctx)
{
  // per-seq slot: h1 (48 x 72 bf16 = 6912B, 16B-aligned), doubling as the
  // x-tile (48 rows x 80B = 3840B) during the conv phase.
  __shared__ __align__(16) __bf16 h1s[4][48 * 72];   // 27648 B
  __shared__ __bf16 wbufs[4][64];                    // 512 B

  const int tid  = threadIdx.x;
  const int lane = tid & 63;
  const int wv   = tid >> 6;
  const int m16  = lane & 15;
  const int quad = lane >> 4;
  const int seq0 = blockIdx.x * 4 + wv * 2;

  __bf16* h1a = h1s[wv * 2 + 0];
  __bf16* h1b = h1s[wv * 2 + 1];
  char* xta = (char*)h1a;              // x-tile views (rows stride 80B)
  char* xtb = (char*)h1b;
  __bf16* wbufa = wbufs[wv * 2 + 0];
  __bf16* wbufb = wbufs[wv * 2 + 1];

  const __bf16* wsb  = (const __bf16*)ws;
  const bf16x8* WccB = (const bf16x8*)(wsb + OFF_WCC);
  const bf16x8* MqkB = (const bf16x8*)(wsb + OFF_MQK);
  const bf16x8* WvB  = (const bf16x8*)(wsb + OFF_WV);
  const float*  wsf  = ws;
  const float*  xsa  = x + (size_t)seq0 * (TT * 32);
  const float*  xsb  = xsa + TT * 32;

  // ---- stage x for BOTH seqs: 12 coalesced float4 loads, one round trip ----
  float4 ga[6], gb[6];
  #pragma unroll
  for (int i = 0; i < 6; ++i) ga[i] = *(const float4*)(xsa + (lane + 64 * i) * 4);
  #pragma unroll
  for (int i = 0; i < 6; ++i) gb[i] = *(const float4*)(xsb + (lane + 64 * i) * 4);

  // ---- bias/kv0 prefetch (shared by both seqs; overlaps x latency) ----
  float bt_[2][2], b0_[2][2], b2_[2][2];
  #pragma unroll
  for (int nh = 0; nh < 2; ++nh)
    #pragma unroll
    for (int j = 0; j < 2; ++j) {
      const int c = nh * 32 + j * 16 + m16;
      bt_[nh][j] = wsf[WS_BTOT + c];
      b0_[nh][j] = wsf[WS_BC0 + c];
      b2_[nh][j] = wsf[WS_BC2 + c];
    }
  float kv0_[4];
  #pragma unroll
  for (int nt = 0; nt < 4; ++nt) kv0_[nt] = wsf[WS_KV0 + nt * 16 + m16];

  // ---- cvt once to bf16, write both x-tiles (chunk c: row c>>3, slot c&7) ----
  #pragma unroll
  for (int i = 0; i < 6; ++i) {
    const int c_ = lane + 64 * i;
    const int off = (c_ >> 3) * 80 + (c_ & 7) * 8;
    *(unsigned long long*)(xta + off) = pack4(ga[i]);
    *(unsigned long long*)(xtb + off) = pack4(gb[i]);
  }
  __asm__ __volatile__("s_waitcnt lgkmcnt(0)" ::: "memory");

  // ---- conv GEMM, BOTH halves at once (acc 96 f32), weights shared ----
  f32x4 acc[2][3][4];   // [seq][mt][nh*2+j]
  #pragma unroll
  for (int s = 0; s < 2; ++s)
    #pragma unroll
    for (int mt = 0; mt < 3; ++mt)
      #pragma unroll
      for (int q = 0; q < 4; ++q) acc[s][mt][q] = zero4();

  #pragma unroll
  for (int ks = 0; ks < 3; ++ks) {
    const int wbase = (ks * 4 + quad) * 64 + m16;
    bf16x8 w0 = WccB[wbase +  0];
    bf16x8 w1 = WccB[wbase + 16];
    bf16x8 w2 = WccB[wbase + 32];
    bf16x8 w3 = WccB[wbase + 48];
    #pragma unroll
    for (int mt = 0; mt < 3; ++mt) {
      const int tg = mt * 16 + m16 + ks - 1;
      const int rc = tg < 0 ? 0 : (tg > 47 ? 47 : tg);
      bf16x8 aa = *(const bf16x8*)(xta + rc * 80 + quad * 16);
      bf16x8 ab = *(const bf16x8*)(xtb + rc * 80 + quad * 16);
      if ((mt == 0 && ks == 0) || (mt == 2 && ks == 2)) {
        bf16x8 z8;
        #pragma unroll
        for (int j = 0; j < 8; ++j) z8[j] = (__bf16)0.f;
        const bool ok = (tg >= 0 && tg < 48);
        aa = ok ? aa : z8;
        ab = ok ? ab : z8;
      }
      acc[0][mt][0] = __builtin_amdgcn_mfma_f32_16x16x32_bf16(aa, w0, acc[0][mt][0], 0, 0, 0);
      acc[1][mt][0] = __builtin_amdgcn_mfma_f32_16x16x32_bf16(ab, w0, acc[1][mt][0], 0, 0, 0);
      acc[0][mt][1] = __builtin_amdgcn_mfma_f32_16x16x32_bf16(aa, w1, acc[0][mt][1], 0, 0, 0);
      acc[1][mt][1] = __builtin_amdgcn_mfma_f32_16x16x32_bf16(ab, w1, acc[1][mt][1], 0, 0, 0);
      acc[0][mt][2] = __builtin_amdgcn_mfma_f32_16x16x32_bf16(aa, w2, acc[0][mt][2], 0, 0, 0);
      acc[1][mt][2] = __builtin_amdgcn_mfma_f32_16x16x32_bf16(ab, w2, acc[1][mt][2], 0, 0, 0);
      acc[0][mt][3] = __builtin_amdgcn_mfma_f32_16x16x32_bf16(aa, w3, acc[0][mt][3], 0, 0, 0);
      acc[1][mt][3] = __builtin_amdgcn_mfma_f32_16x16x32_bf16(ab, w3, acc[1][mt][3], 0, 0, 0);
    }
  }
  // all x-tile reads retired (consumed by MFMAs; DS is in-order per wave) --
  // safe to overwrite the union region with h1 now.
  __asm__ __volatile__("s_waitcnt lgkmcnt(0)" ::: "memory");

  // ---- epilogue both seqs: bias (+pad-row fix), relu, bf16 -> h1 (stride 72) ----
  #pragma unroll
  for (int s = 0; s < 2; ++s) {
    __bf16* h1 = s ? h1b : h1a;
    #pragma unroll
    for (int nh = 0; nh < 2; ++nh)
      #pragma unroll
      for (int j = 0; j < 2; ++j) {
        const int c = nh * 32 + j * 16 + m16;
        const float bt  = bt_[nh][j];
        const float b0v = b0_[nh][j];
        const float b2v = b2_[nh][j];
        #pragma unroll
        for (int mt = 0; mt < 3; ++mt)
          #pragma unroll
          for (int r = 0; r < 4; ++r) {
            const int trow = mt * 16 + quad * 4 + r;
            float v = acc[s][mt][nh * 2 + j][r] + bt;
            if (mt == 0 && r == 0 && quad == 0) v -= b0v;   // t==0
            if (mt == 2 && r == 3 && quad == 3) v -= b2v;   // t==47
            h1[trow * 72 + c] = (__bf16)fmaxf(v, 0.f);
          }
      }
  }
  __asm__ __volatile__("s_waitcnt lgkmcnt(0)" ::: "memory");

  // ---- A-fragments of h1, both seqs (shared by w-GEMV, scores, v) ----
  bf16x8 a8[2][3][2];
  #pragma unroll
  for (int mt = 0; mt < 3; ++mt)
    #pragma unroll
    for (int ks = 0; ks < 2; ++ks) {
      const int off = (mt * 16 + m16) * 72 + ks * 32 + quad * 8;
      a8[0][mt][ks] = *(const bf16x8*)&h1a[off];
      a8[1][mt][ks] = *(const bf16x8*)&h1b[off];
    }

  // ---- w-GEMV: w = 0.125*(Wq Wk^T)^T h1_47 + kv0 (Mqk frags shared) ----
  {
    bf16x8 mq[2][4];
    #pragma unroll
    for (int ks = 0; ks < 2; ++ks)
      #pragma unroll
      for (int nt = 0; nt < 4; ++nt)
        mq[ks][nt] = MqkB[(ks * 4 + quad) * 64 + nt * 16 + m16];
    f32x4 qa[2][4];
    #pragma unroll
    for (int s = 0; s < 2; ++s)
      #pragma unroll
      for (int nt = 0; nt < 4; ++nt) qa[s][nt] = zero4();
    #pragma unroll
    for (int ks = 0; ks < 2; ++ks)
      #pragma unroll
      for (int nt = 0; nt < 4; ++nt) {
        qa[0][nt] = __builtin_amdgcn_mfma_f32_16x16x32_bf16(a8[0][2][ks], mq[ks][nt], qa[0][nt], 0, 0, 0);
        qa[1][nt] = __builtin_amdgcn_mfma_f32_16x16x32_bf16(a8[1][2][ks], mq[ks][nt], qa[1][nt], 0, 0, 0);
      }
    if (quad == 3) {   // row 47 = quad 3, reg 3; lane holds w[nt*16+m16]
      #pragma unroll
      for (int nt = 0; nt < 4; ++nt) {
        wbufa[nt * 16 + m16] = (__bf16)(qa[0][nt][3] + kv0_[nt]);
        wbufb[nt * 16 + m16] = (__bf16)(qa[1][nt][3] + kv0_[nt]);
      }
    }
  }
  __asm__ __volatile__("s_waitcnt lgkmcnt(0)" ::: "memory");

  // ---- scores-GEMV with broadcast-w B-frags; softmax per seq ----
  float p[2][3][4];
  #pragma unroll
  for (int s = 0; s < 2; ++s) {
    const __bf16* wbuf = s ? wbufb : wbufa;
    bf16x8 wB0 = *(const bf16x8*)&wbuf[quad * 8];
    bf16x8 wB1 = *(const bf16x8*)&wbuf[32 + quad * 8];
    f32x4 sa[3] = {zero4(), zero4(), zero4()};
    #pragma unroll
    for (int mt = 0; mt < 3; ++mt) {
      sa[mt] = __builtin_amdgcn_mfma_f32_16x16x32_bf16(a8[s][mt][0], wB0, sa[mt], 0, 0, 0);
      sa[mt] = __builtin_amdgcn_mfma_f32_16x16x32_bf16(a8[s][mt][1], wB1, sa[mt], 0, 0, 0);
    }
    float mx = -INFINITY;
    #pragma unroll
    for (int mt = 0; mt < 3; ++mt)
      #pragma unroll
      for (int r = 0; r < 4; ++r) mx = fmaxf(mx, sa[mt][r]);
    mx = fmaxf(mx, __shfl_xor(mx, 16, 64));
    mx = fmaxf(mx, __shfl_xor(mx, 32, 64));
    float l = 0.f;
    #pragma unroll
    for (int mt = 0; mt < 3; ++mt)
      #pragma unroll
      for (int r = 0; r < 4; ++r) {
        float e = __expf(sa[mt][r] - mx);
        p[s][mt][r] = e;
        l += e;
      }
    l += __shfl_xor(l, 16, 64);
    l += __shfl_xor(l, 32, 64);
    float rl = 1.f / l;
    #pragma unroll
    for (int mt = 0; mt < 3; ++mt)
      #pragma unroll
      for (int r = 0; r < 4; ++r) p[s][mt][r] *= rl;
  }

  // ---- v pass (two halves, Wv frags shared) + ctx in registers ----
  {
    float cx[2][4];
    #pragma unroll
    for (int nh = 0; nh < 2; ++nh) {
      bf16x8 vb[2][2];
      #pragma unroll
      for (int ks = 0; ks < 2; ++ks) {
        vb[ks][0] = WvB[(ks * 4 + quad) * 64 + nh * 32 + m16];
        vb[ks][1] = WvB[(ks * 4 + quad) * 64 + nh * 32 + 16 + m16];
      }
      f32x4 va[2][3][2];
      #pragma unroll
      for (int s = 0; s < 2; ++s)
        #pragma unroll
        for (int mt = 0; mt < 3; ++mt) { va[s][mt][0] = zero4(); va[s][mt][1] = zero4(); }
      #pragma unroll
      for (int ks = 0; ks < 2; ++ks)
        #pragma unroll
        for (int mt = 0; mt < 3; ++mt) {
          va[0][mt][0] = __builtin_amdgcn_mfma_f32_16x16x32_bf16(a8[0][mt][ks], vb[ks][0], va[0][mt][0], 0, 0, 0);
          va[1][mt][0] = __builtin_amdgcn_mfma_f32_16x16x32_bf16(a8[1][mt][ks], vb[ks][0], va[1][mt][0], 0, 0, 0);
          va[0][mt][1] = __builtin_amdgcn_mfma_f32_16x16x32_bf16(a8[0][mt][ks], vb[ks][1], va[0][mt][1], 0, 0, 0);
          va[1][mt][1] = __builtin_amdgcn_mfma_f32_16x16x32_bf16(a8[1][mt][ks], vb[ks][1], va[1][mt][1], 0, 0, 0);
        }
      #pragma unroll
      for (int s = 0; s < 2; ++s)
        #pragma unroll
        for (int j = 0; j < 2; ++j) {
          float a = 0.f;
          #pragma unroll
          for (int mt = 0; mt < 3; ++mt)
            #pragma unroll
            for (int r = 0; r < 4; ++r)
              a = fmaf(p[s][mt][r], va[s][mt][j][r], a);
          cx[s][nh * 2 + j] = a;
        }
    }
    #pragma unroll
    for (int s = 0; s < 2; ++s)
      #pragma unroll
      for (int nt = 0; nt < 4; ++nt) {
        cx[s][nt] += __shfl_xor(cx[s][nt], 16, 64);
        cx[s][nt] += __shfl_xor(cx[s][nt], 32, 64);
      }
    if (quad == 0) {
      #pragma unroll
      for (int nt = 0; nt < 4; ++nt) {
        const float bvv = bv[nt * 16 + m16];
        ctx[(size_t)(seq0 + 0) * 64 + nt * 16 + m16] = cx[0][nt] + bvv;
        ctx[(size_t)(seq0 + 1) * 64 + nt * 16 + m16] = cx[1][nt] + bvv;
      }
    }
  }
}

// ---------------------------------------------------------------------------
// MLP kernel (MFMA layers 1-2, fp32 layer 3): 16 rows/block, 2048 blocks
// (8/CU).  Xs padded stride 68; layer 3 uses 4 accumulators + float4 z2.
// ---------------------------------------------------------------------------
__global__ __launch_bounds__(256) void mlp_kernel(
    const float* __restrict__ ctx, const float* __restrict__ ws,
    const float* __restrict__ b1, const float* __restrict__ b2,
    const float* __restrict__ W3, const float* __restrict__ b3,
    float* __restrict__ out)
{
  __shared__ __bf16 Xs[16 * 68];    // 2176 B
  __shared__ __bf16 z1[16 * 264];   // 8448 B
  __shared__ float  z2[16 * 132];   // 8448 B

  const int tid  = threadIdx.x;
  const int r0   = blockIdx.x * 16;
  const int lane = tid & 63;
  const int wv   = tid >> 6;
  const int m16  = lane & 15;
  const int quad = lane >> 4;

  const __bf16* wsb = (const __bf16*)ws;
  const bf16x8* W1B = (const bf16x8*)(wsb + OFF_W1);
  const bf16x8* W2B = (const bf16x8*)(wsb + OFF_W2);

  // load 16 ctx rows (1024 floats = 256 float4), cast bf16 -> Xs
  {
    int row = tid >> 4, c4 = (tid & 15) * 4;
    float4 a = *(const float4*)(ctx + (size_t)(r0 + row) * 64 + c4);
    __bf16* d = &Xs[row * 68 + c4];
    d[0] = (__bf16)a.x; d[1] = (__bf16)a.y; d[2] = (__bf16)a.z; d[3] = (__bf16)a.w;
  }
  __syncthreads();

  // ---- layer 1: M=16 N=256 K=64; wave covers n in [wv*64, wv*64+64) ----
  {
    bf16x8 a8[2];
    #pragma unroll
    for (int ks = 0; ks < 2; ++ks)
      a8[ks] = *(const bf16x8*)&Xs[m16 * 68 + ks * 32 + quad * 8];
    f32x4 acc[4] = {zero4(), zero4(), zero4(), zero4()};
    #pragma unroll
    for (int nt = 0; nt < 4; ++nt) {
      int n = wv * 64 + nt * 16 + m16;
      #pragma unroll
      for (int ks = 0; ks < 2; ++ks)
        acc[nt] = __builtin_amdgcn_mfma_f32_16x16x32_bf16(
            a8[ks], W1B[(ks * 4 + quad) * 256 + n], acc[nt], 0, 0, 0);
    }
    #pragma unroll
    for (int nt = 0; nt < 4; ++nt) {
      int n = wv * 64 + nt * 16 + m16;
      float bb = b1[n];
      #pragma unroll
      for (int r = 0; r < 4; ++r)
        z1[(quad * 4 + r) * 264 + n] = (__bf16)fmaxf(acc[nt][r] + bb, 0.f);
    }
  }
  __syncthreads();

  // ---- layer 2: M=16 N=128 K=256; wave covers n in [wv*32, wv*32+32) ----
  {
    f32x4 acc[2] = {zero4(), zero4()};
    #pragma unroll 2
    for (int ks = 0; ks < 8; ++ks) {
      bf16x8 a = *(const bf16x8*)&z1[m16 * 264 + ks * 32 + quad * 8];
      #pragma unroll
      for (int nt = 0; nt < 2; ++nt)
        acc[nt] = __builtin_amdgcn_mfma_f32_16x16x32_bf16(
            a, W2B[(ks * 4 + quad) * 128 + wv * 32 + nt * 16 + m16], acc[nt], 0, 0, 0);
    }
    #pragma unroll
    for (int nt = 0; nt < 2; ++nt) {
      int n = wv * 32 + nt * 16 + m16;
      float bb = b2[n];
      #pragma unroll
      for (int r = 0; r < 4; ++r)
        z2[(quad * 4 + r) * 132 + n] = fmaxf(acc[nt][r] + bb, 0.f);
    }
  }
  __syncthreads();

  // ---- layer 3 (fp32, 16x12 K=128) + transposed store out[b][p][n] ----
  if (tid < 16 * NP) {
    int r = tid / NP, pp = tid - r * NP;
    const float* zr = z2 + r * 132;
    float a0 = b3[pp], a1 = 0.f, a2 = 0.f, a3 = 0.f;
    #pragma unroll 8
    for (int k = 0; k < 128; k += 4) {
      float4 f = *(const float4*)(zr + k);
      a0 = fmaf(f.x, W3[k * NP + pp],       a0);
      a1 = fmaf(f.y, W3[(k + 1) * NP + pp], a1);
      a2 = fmaf(f.z, W3[(k + 2) * NP + pp], a2);
      a3 = fmaf(f.w, W3[(k + 3) * NP + pp], a3);
    }
    float a = (a0 + a1) + (a2 + a3);
    int row = r0 + r;
    int bb = row >> 11, nn = row & 2047;
    out[(size_t)bb * (NP * 2048) + pp * 2048 + nn] = a;
  }
}

// ---------------------------------------------------------------------------
extern "C" void kernel_launch(void* const* d_in, const int* in_sizes, int n_in,
                              void* d_out, int out_size, void* d_ws, size_t ws_size,
                              hipStream_t stream) {
  const float* x      = (const float*)d_in[0];
  const float* W_in   = (const float*)d_in[1];
  const float* b_in   = (const float*)d_in[2];
  const float* W_conv = (const float*)d_in[3];
  const float* b_conv = (const float*)d_in[4];
  const float* Wq     = (const float*)d_in[5];
  const float* bq     = (const float*)d_in[6];
  const float* Wk     = (const float*)d_in[7];
  const float* bk     = (const float*)d_in[8];  (void)bk;
  const float* Wv     = (const float*)d_in[9];
  const float* bv     = (const float*)d_in[10];
  const float* W1     = (const float*)d_in[11];
  const float* b1     = (const float*)d_in[12];
  const float* W2     = (const float*)d_in[13];
  const float* b2     = (const float*)d_in[14];
  const float* W3     = (const float*)d_in[15];
  const float* b3     = (const float*)d_in[16];
  float* ws  = (float*)d_ws;
  float* out = (float*)d_out;

  prep_kernel<<<249, 256, 0, stream>>>(W_in, b_in, W_conv, b_conv, Wk, Wv, Wq, bq, W1, W2, ws);
  attn_kernel<<<NSEQ / 4, 128, 0, stream>>>(x, bv, ws, ws + WS_CTX);
  mlp_kernel<<<NSEQ / 16, 256, 0, stream>>>(ws + WS_CTX, ws, b1, b2, W3, b3, out);
}

// Round 6
// 332.672 us; speedup vs baseline: 1.0281x; 1.0281x over previous
//
#include <hip/hip_runtime.h>
#include <hip/hip_bf16.h>
#include <math.h>

// Problem constants
#define TT 48
#define NSEQ (16*2048)
#define NP 12

// MFMA fragment types (gfx950: mfma_f32_16x16x32_bf16)
typedef __bf16 bf16x8 __attribute__((ext_vector_type(8)));
typedef float  f32x4  __attribute__((ext_vector_type(4)));

// ws layout.
// bf16 region (ws viewed as __bf16*), all B-frag swizzled [((k>>3)*N + n)*8 + (k&7)]:
//   [0)      WccB  96x64   (folded W_in @ W_conv)
//   [6144)   MqkB  64x64   (0.125 * Wq @ Wk^T, k-index = d, n-index = c)
//   [10240)  WvB   64x64
//   [18432)  W1B   64x256
//   [34816)  W2B   256x128   -> ends 67584 bf16 == float idx 33792
// float region (ws viewed as float*):
//   [33792)  btot 64   (bc0+bc1+bc2+b_conv)
//   [33856)  bc0  64
//   [33920)  bc2  64
//   [33984)  kv0  64   (0.125 * Wk @ bq)
//   [34048)  ctx  32768*64
#define OFF_WCC 0
#define OFF_MQK 6144
#define OFF_WV  10240
#define OFF_W1  18432
#define OFF_W2  34816
#define WS_BTOT 33792
#define WS_BC0  33856
#define WS_BC2  33920
#define WS_KV0  33984
#define WS_CTX  34048

__device__ __forceinline__ f32x4 zero4() {
  f32x4 z; z[0] = 0.f; z[1] = 0.f; z[2] = 0.f; z[3] = 0.f; return z;
}

union PackU { bf16x8 v; __hip_bfloat162 h[4]; };
union Pack4 { unsigned long long u; __hip_bfloat162 h[2]; };

// packed fp32x8 -> bf16x8 conversion (v_cvt_pk_bf16_f32)
__device__ __forceinline__ bf16x8 pack8(float4 a, float4 b) {
  PackU u;
  u.h[0] = __float22bfloat162_rn(make_float2(a.x, a.y));
  u.h[1] = __float22bfloat162_rn(make_float2(a.z, a.w));
  u.h[2] = __float22bfloat162_rn(make_float2(b.x, b.y));
  u.h[3] = __float22bfloat162_rn(make_float2(b.z, b.w));
  return u.v;
}

// packed fp32x4 -> 4x bf16 (8B) conversion
__device__ __forceinline__ unsigned long long pack4(float4 a) {
  Pack4 u;
  u.h[0] = __float22bfloat162_rn(make_float2(a.x, a.y));
  u.h[1] = __float22bfloat162_rn(make_float2(a.z, a.w));
  return u.u;
}

// ---------------------------------------------------------------------------
// Prep: fold W_in into conv weights; precompute M_qk = 0.125*Wq@Wk^T and
// kv0 = 0.125*Wk@bq (softmax shift-invariance kills all other q/k terms);
// convert all GEMM weights to bf16 in B-frag-swizzled order.
// ---------------------------------------------------------------------------
__global__ __launch_bounds__(256) void prep_kernel(
    const float* __restrict__ W_in, const float* __restrict__ b_in,
    const float* __restrict__ W_conv, const float* __restrict__ b_conv,
    const float* __restrict__ Wk, const float* __restrict__ Wv,
    const float* __restrict__ Wq, const float* __restrict__ bq,
    const float* __restrict__ W1, const float* __restrict__ W2,
    float* __restrict__ ws)
{
  __bf16* wsb = (__bf16*)ws;
  const int tid = threadIdx.x;
  const int bid = blockIdx.x;
  if (bid < 24) {                       // WccB: fold W_in into W_conv
    int gid = bid * 256 + tid;          // 0..6143
    int kk = gid >> 6;                  // 0..95
    int c  = gid & 63;
    int dt = kk >> 5;
    int e  = kk & 31;
    const float* wrow = W_in + e * 64;
    const float* wc   = W_conv + dt * 4096 + c;
    float acc = 0.f;
    #pragma unroll 8
    for (int c0 = 0; c0 < 64; ++c0)
      acc = fmaf(wrow[c0], wc[c0 * 64], acc);
    wsb[OFF_WCC + ((kk >> 3) * 64 + c) * 8 + (kk & 7)] = (__bf16)acc;
  } else if (bid < 40) {                // MqkB = 0.125 * Wq @ Wk^T  (k=d, n=c)
    int gid = (bid - 24) * 256 + tid;   // 0..4095
    int d = gid >> 6, c = gid & 63;
    const float* qr = Wq + d * 64;
    const float* kr = Wk + c * 64;
    float acc = 0.f;
    #pragma unroll 8
    for (int j = 0; j < 64; ++j) acc = fmaf(qr[j], kr[j], acc);
    wsb[OFF_MQK + ((d >> 3) * 64 + c) * 8 + (d & 7)] = (__bf16)(0.125f * acc);
  } else if (bid < 56) {                // WvB
    int gid = (bid - 40) * 256 + tid;
    int kk = gid >> 6, c = gid & 63;
    wsb[OFF_WV + ((kk >> 3) * 64 + c) * 8 + (kk & 7)] = (__bf16)Wv[kk * 64 + c];
  } else if (bid < 120) {               // W1B (64x256)
    int gid = (bid - 56) * 256 + tid;   // 0..16383
    int kk = gid >> 8, n = gid & 255;
    wsb[OFF_W1 + ((kk >> 3) * 256 + n) * 8 + (kk & 7)] = (__bf16)W1[kk * 256 + n];
  } else if (bid < 248) {               // W2B (256x128)
    int gid = (bid - 120) * 256 + tid;  // 0..32767
    int kk = gid >> 7, n = gid & 127;
    wsb[OFF_W2 + ((kk >> 3) * 128 + n) * 8 + (kk & 7)] = (__bf16)W2[kk * 128 + n];
  } else if (tid < 64) {                // biases + kv0
    int c = tid;
    float s[3];
    for (int dt = 0; dt < 3; ++dt) {
      const float* wc = W_conv + dt * 4096 + c;
      float a = 0.f;
      for (int c0 = 0; c0 < 64; ++c0) a = fmaf(b_in[c0], wc[c0 * 64], a);
      s[dt] = a;
    }
    ws[WS_BC0 + c]  = s[0];
    ws[WS_BC2 + c]  = s[2];
    ws[WS_BTOT + c] = s[0] + s[1] + s[2] + b_conv[c];
    float a = 0.f;
    const float* kr = Wk + c * 64;
    for (int j = 0; j < 64; ++j) a = fmaf(kr[j], bq[j], a);
    ws[WS_KV0 + c] = 0.125f * a;
  }
}

// ---------------------------------------------------------------------------
// Attention kernel: ONE WAVE = ONE SEQUENCE, block = 128 threads (2 seqs).
// No __syncthreads.  Algebraically reduced attention:
//   scores[t] = h1[t] . w,  w = MqkB-GEMV(h1[47]) + kv0   (k/q passes gone)
//   scores-GEMV uses broadcast-w B-frags -> scores replicated across all 16
//   C columns -> softmax needs only 4 cross-quad shuffles (was 48+).
//   ctx = sum_t p[t] * V[t] + bv (v-pass MFMA, per-lane weighting).
// ROUND-4 BASE (best measured: attn ~94us) + two latency-hiding edits:
//  - Mqk B-frags issued BEFORE the conv MFMA chain (L2 latency hides under
//    ~36 MFMAs) instead of right before their wGEMV consumers;
//  - Wv B-frags issued BEFORE the softmax (hides under exp/shuffle VALU);
//  - s_setprio(1) around the conv and v-pass MFMA clusters (T5: positive
//    regime = independent waves at different phases, no barriers).
// Round-5 lesson reverted: 2-seq/wave + (128,2) lost residency (VGPR cap)
// for no serial-latency gain.  (128,4) is the proven spill-free config.
// ---------------------------------------------------------------------------
__global__ __launch_bounds__(128, 4) void attn_kernel(
    const float* __restrict__ x, const float* __restrict__ bv,
    const float* __restrict__ ws, float* __restrict__ ctx)
{
  __shared__ __align__(16) __bf16 h1s[2][48 * 72];   // 13824 B
  __shared__ __align__(16) __bf16 xts[2][48 * 40];   // 7680 B (rows 80B)
  __shared__ __bf16 wbufs[2][64];                    // 256 B

  const int tid  = threadIdx.x;
  const int lane = tid & 63;
  const int wv   = tid >> 6;
  const int m16  = lane & 15;
  const int quad = lane >> 4;
  const int seq  = blockIdx.x * 2 + wv;
  __bf16* h1   = h1s[wv];
  __bf16* wbuf = wbufs[wv];
  char* xt = (char*)xts[wv];           // x-tile view (rows stride 80B)

  const __bf16* wsb  = (const __bf16*)ws;
  const bf16x8* WccB = (const bf16x8*)(wsb + OFF_WCC);
  const bf16x8* MqkB = (const bf16x8*)(wsb + OFF_MQK);
  const bf16x8* WvB  = (const bf16x8*)(wsb + OFF_WV);
  const float*  wsf  = ws;
  const float*  xseq = x + (size_t)seq * (TT * 32);

  // ---- stage x: 6 coalesced float4 loads/lane (one round trip) ----
  float4 xg0 = *(const float4*)(xseq + (lane +   0) * 4);
  float4 xg1 = *(const float4*)(xseq + (lane +  64) * 4);
  float4 xg2 = *(const float4*)(xseq + (lane + 128) * 4);
  float4 xg3 = *(const float4*)(xseq + (lane + 192) * 4);
  float4 xg4 = *(const float4*)(xseq + (lane + 256) * 4);
  float4 xg5 = *(const float4*)(xseq + (lane + 320) * 4);

  // ---- bias/kv0 prefetch (L2-hot; overlaps the x-load latency) ----
  float bt_[2][2], b0_[2][2], b2_[2][2];
  #pragma unroll
  for (int nh = 0; nh < 2; ++nh)
    #pragma unroll
    for (int j = 0; j < 2; ++j) {
      const int c = nh * 32 + j * 16 + m16;
      bt_[nh][j] = wsf[WS_BTOT + c];
      b0_[nh][j] = wsf[WS_BC0 + c];
      b2_[nh][j] = wsf[WS_BC2 + c];
    }
  float kv0_[4];
  #pragma unroll
  for (int nt = 0; nt < 4; ++nt) kv0_[nt] = wsf[WS_KV0 + nt * 16 + m16];

  // ---- cvt once to bf16, write x-tile rows (chunk c: row c>>3, 8B slot c&7) ----
  {
    #define XSTORE(i, g) { \
      const int c_ = lane + 64 * (i); \
      *(unsigned long long*)(xt + (c_ >> 3) * 80 + (c_ & 7) * 8) = pack4(g); }
    XSTORE(0, xg0) XSTORE(1, xg1) XSTORE(2, xg2)
    XSTORE(3, xg3) XSTORE(4, xg4) XSTORE(5, xg5)
    #undef XSTORE
  }
  // fence: x-tile writes before fragment reads (same wave, compiler guard)
  __asm__ __volatile__("s_waitcnt lgkmcnt(0)" ::: "memory");

  // ---- issue Mqk frag loads NOW: L2 latency hides under the conv MFMAs ----
  bf16x8 mq[2][4];
  #pragma unroll
  for (int ks = 0; ks < 2; ++ks)
    #pragma unroll
    for (int nt = 0; nt < 4; ++nt)
      mq[ks][nt] = MqkB[(ks * 4 + quad) * 64 + nt * 16 + m16];

  // ---- conv GEMM in two 32-channel halves; A-frags read per-use from LDS ----
  __builtin_amdgcn_s_setprio(1);
  #pragma unroll
  for (int nh = 0; nh < 2; ++nh) {
    f32x4 acc[3][2];
    #pragma unroll
    for (int mt = 0; mt < 3; ++mt) { acc[mt][0] = zero4(); acc[mt][1] = zero4(); }
    #pragma unroll
    for (int ks = 0; ks < 3; ++ks) {
      bf16x8 b0 = WccB[(ks * 4 + quad) * 64 + nh * 32 + m16];
      bf16x8 b1 = WccB[(ks * 4 + quad) * 64 + nh * 32 + 16 + m16];
      #pragma unroll
      for (int mt = 0; mt < 3; ++mt) {
        const int tg = mt * 16 + m16 + ks - 1;
        const int rc = tg < 0 ? 0 : (tg > 47 ? 47 : tg);
        bf16x8 a = *(const bf16x8*)(xt + rc * 80 + quad * 16);
        if ((mt == 0 && ks == 0) || (mt == 2 && ks == 2)) {
          bf16x8 z8;
          #pragma unroll
          for (int j = 0; j < 8; ++j) z8[j] = (__bf16)0.f;
          a = (tg >= 0 && tg < 48) ? a : z8;
        }
        acc[mt][0] = __builtin_amdgcn_mfma_f32_16x16x32_bf16(a, b0, acc[mt][0], 0, 0, 0);
        acc[mt][1] = __builtin_amdgcn_mfma_f32_16x16x32_bf16(a, b1, acc[mt][1], 0, 0, 0);
      }
    }
    // epilogue: bias (+pad-row fix), relu, bf16 -> LDS h1 (stride 72)
    #pragma unroll
    for (int j = 0; j < 2; ++j) {
      const int c = nh * 32 + j * 16 + m16;
      const float bt  = bt_[nh][j];
      const float b0v = b0_[nh][j];
      const float b2v = b2_[nh][j];
      #pragma unroll
      for (int mt = 0; mt < 3; ++mt)
        #pragma unroll
        for (int r = 0; r < 4; ++r) {
          const int trow = mt * 16 + quad * 4 + r;
          float v = acc[mt][j][r] + bt;
          if (mt == 0 && r == 0 && quad == 0) v -= b0v;   // t==0
          if (mt == 2 && r == 3 && quad == 3) v -= b2v;   // t==47
          h1[trow * 72 + c] = (__bf16)fmaxf(v, 0.f);
        }
    }
  }
  __builtin_amdgcn_s_setprio(0);
  // within-wave LDS write->read fence (no barrier: one wave owns its seq)
  __asm__ __volatile__("s_waitcnt lgkmcnt(0)" ::: "memory");

  // ---- A-fragments of h1 (shared by w-GEMV, scores, v); b128-aligned ----
  bf16x8 a8[3][2];
  #pragma unroll
  for (int mt = 0; mt < 3; ++mt)
    #pragma unroll
    for (int ks = 0; ks < 2; ++ks)
      a8[mt][ks] = *(const bf16x8*)&h1[(mt * 16 + m16) * 72 + ks * 32 + quad * 8];

  // ---- w-GEMV: w = 0.125*(Wq Wk^T)^T h1_47 + kv0 (mq prefetched above) ----
  {
    f32x4 qa[4] = {zero4(), zero4(), zero4(), zero4()};
    #pragma unroll
    for (int ks = 0; ks < 2; ++ks)
      #pragma unroll
      for (int nt = 0; nt < 4; ++nt)
        qa[nt] = __builtin_amdgcn_mfma_f32_16x16x32_bf16(
            a8[2][ks], mq[ks][nt], qa[nt], 0, 0, 0);
    if (quad == 3) {   // row 47 = quad 3, reg 3; lane holds w[nt*16+m16]
      #pragma unroll
      for (int nt = 0; nt < 4; ++nt)
        wbuf[nt * 16 + m16] = (__bf16)(qa[nt][3] + kv0_[nt]);
    }
  }
  __asm__ __volatile__("s_waitcnt lgkmcnt(0)" ::: "memory");

  // ---- issue Wv frag loads NOW: latency hides under softmax VALU ----
  bf16x8 vb[2][2][2];   // [nh][ks][j]
  #pragma unroll
  for (int nh = 0; nh < 2; ++nh)
    #pragma unroll
    for (int ks = 0; ks < 2; ++ks) {
      vb[nh][ks][0] = WvB[(ks * 4 + quad) * 64 + nh * 32 + m16];
      vb[nh][ks][1] = WvB[(ks * 4 + quad) * 64 + nh * 32 + 16 + m16];
    }

  // ---- scores-GEMV with broadcast-w B-frags: C[t][n] = scores[t] for all n ----
  float p[3][4];
  {
    bf16x8 wB0 = *(const bf16x8*)&wbuf[quad * 8];
    bf16x8 wB1 = *(const bf16x8*)&wbuf[32 + quad * 8];
    f32x4 sa[3] = {zero4(), zero4(), zero4()};
    #pragma unroll
    for (int mt = 0; mt < 3; ++mt) {
      sa[mt] = __builtin_amdgcn_mfma_f32_16x16x32_bf16(a8[mt][0], wB0, sa[mt], 0, 0, 0);
      sa[mt] = __builtin_amdgcn_mfma_f32_16x16x32_bf16(a8[mt][1], wB1, sa[mt], 0, 0, 0);
    }
    // softmax over 48 t: 12 logits/lane (replicated across m16), cross-quad only
    float mx = -INFINITY;
    #pragma unroll
    for (int mt = 0; mt < 3; ++mt)
      #pragma unroll
      for (int r = 0; r < 4; ++r) mx = fmaxf(mx, sa[mt][r]);
    mx = fmaxf(mx, __shfl_xor(mx, 16, 64));
    mx = fmaxf(mx, __shfl_xor(mx, 32, 64));
    float l = 0.f;
    #pragma unroll
    for (int mt = 0; mt < 3; ++mt)
      #pragma unroll
      for (int r = 0; r < 4; ++r) {
        float e = __expf(sa[mt][r] - mx);
        p[mt][r] = e;
        l += e;
      }
    l += __shfl_xor(l, 16, 64);
    l += __shfl_xor(l, 32, 64);
    float rl = 1.f / l;
    #pragma unroll
    for (int mt = 0; mt < 3; ++mt)
      #pragma unroll
      for (int r = 0; r < 4; ++r) p[mt][r] *= rl;
  }

  // ---- v pass (two halves, vb prefetched) + ctx in registers ----
  {
    float cx[4];
    __builtin_amdgcn_s_setprio(1);
    #pragma unroll
    for (int nh = 0; nh < 2; ++nh) {
      f32x4 va[3][2];
      #pragma unroll
      for (int mt = 0; mt < 3; ++mt) { va[mt][0] = zero4(); va[mt][1] = zero4(); }
      #pragma unroll
      for (int ks = 0; ks < 2; ++ks) {
        #pragma unroll
        for (int mt = 0; mt < 3; ++mt) {
          va[mt][0] = __builtin_amdgcn_mfma_f32_16x16x32_bf16(a8[mt][ks], vb[nh][ks][0], va[mt][0], 0, 0, 0);
          va[mt][1] = __builtin_amdgcn_mfma_f32_16x16x32_bf16(a8[mt][ks], vb[nh][ks][1], va[mt][1], 0, 0, 0);
        }
      }
      #pragma unroll
      for (int j = 0; j < 2; ++j) {
        float a = 0.f;
        #pragma unroll
        for (int mt = 0; mt < 3; ++mt)
          #pragma unroll
          for (int r = 0; r < 4; ++r)
            a = fmaf(p[mt][r], va[mt][j][r], a);
        cx[nh * 2 + j] = a;
      }
    }
    __builtin_amdgcn_s_setprio(0);
    #pragma unroll
    for (int nt = 0; nt < 4; ++nt) {
      cx[nt] += __shfl_xor(cx[nt], 16, 64);
      cx[nt] += __shfl_xor(cx[nt], 32, 64);
    }
    if (quad == 0) {
      #pragma unroll
      for (int nt = 0; nt < 4; ++nt)
        ctx[(size_t)seq * 64 + nt * 16 + m16] = cx[nt] + bv[nt * 16 + m16];
    }
  }
}

// ---------------------------------------------------------------------------
// MLP kernel (MFMA layers 1-2, fp32 layer 3): 16 rows/block, 2048 blocks
// (8/CU).  Xs padded stride 68; layer 3 uses 4 accumulators + float4 z2.
// ---------------------------------------------------------------------------
__global__ __launch_bounds__(256) void mlp_kernel(
    const float* __restrict__ ctx, const float* __restrict__ ws,
    const float* __restrict__ b1, const float* __restrict__ b2,
    const float* __restrict__ W3, const float* __restrict__ b3,
    float* __restrict__ out)
{
  __shared__ __bf16 Xs[16 * 68];    // 2176 B
  __shared__ __bf16 z1[16 * 264];   // 8448 B
  __shared__ float  z2[16 * 132];   // 8448 B

  const int tid  = threadIdx.x;
  const int r0   = blockIdx.x * 16;
  const int lane = tid & 63;
  const int wv   = tid >> 6;
  const int m16  = lane & 15;
  const int quad = lane >> 4;

  const __bf16* wsb = (const __bf16*)ws;
  const bf16x8* W1B = (const bf16x8*)(wsb + OFF_W1);
  const bf16x8* W2B = (const bf16x8*)(wsb + OFF_W2);

  // load 16 ctx rows (1024 floats = 256 float4), cast bf16 -> Xs
  {
    int row = tid >> 4, c4 = (tid & 15) * 4;
    float4 a = *(const float4*)(ctx + (size_t)(r0 + row) * 64 + c4);
    __bf16* d = &Xs[row * 68 + c4];
    d[0] = (__bf16)a.x; d[1] = (__bf16)a.y; d[2] = (__bf16)a.z; d[3] = (__bf16)a.w;
  }
  __syncthreads();

  // ---- layer 1: M=16 N=256 K=64; wave covers n in [wv*64, wv*64+64) ----
  {
    bf16x8 a8[2];
    #pragma unroll
    for (int ks = 0; ks < 2; ++ks)
      a8[ks] = *(const bf16x8*)&Xs[m16 * 68 + ks * 32 + quad * 8];
    f32x4 acc[4] = {zero4(), zero4(), zero4(), zero4()};
    #pragma unroll
    for (int nt = 0; nt < 4; ++nt) {
      int n = wv * 64 + nt * 16 + m16;
      #pragma unroll
      for (int ks = 0; ks < 2; ++ks)
        acc[nt] = __builtin_amdgcn_mfma_f32_16x16x32_bf16(
            a8[ks], W1B[(ks * 4 + quad) * 256 + n], acc[nt], 0, 0, 0);
    }
    #pragma unroll
    for (int nt = 0; nt < 4; ++nt) {
      int n = wv * 64 + nt * 16 + m16;
      float bb = b1[n];
      #pragma unroll
      for (int r = 0; r < 4; ++r)
        z1[(quad * 4 + r) * 264 + n] = (__bf16)fmaxf(acc[nt][r] + bb, 0.f);
    }
  }
  __syncthreads();

  // ---- layer 2: M=16 N=128 K=256; wave covers n in [wv*32, wv*32+32) ----
  {
    f32x4 acc[2] = {zero4(), zero4()};
    #pragma unroll 2
    for (int ks = 0; ks < 8; ++ks) {
      bf16x8 a = *(const bf16x8*)&z1[m16 * 264 + ks * 32 + quad * 8];
      #pragma unroll
      for (int nt = 0; nt < 2; ++nt)
        acc[nt] = __builtin_amdgcn_mfma_f32_16x16x32_bf16(
            a, W2B[(ks * 4 + quad) * 128 + wv * 32 + nt * 16 + m16], acc[nt], 0, 0, 0);
    }
    #pragma unroll
    for (int nt = 0; nt < 2; ++nt) {
      int n = wv * 32 + nt * 16 + m16;
      float bb = b2[n];
      #pragma unroll
      for (int r = 0; r < 4; ++r)
        z2[(quad * 4 + r) * 132 + n] = fmaxf(acc[nt][r] + bb, 0.f);
    }
  }
  __syncthreads();

  // ---- layer 3 (fp32, 16x12 K=128) + transposed store out[b][p][n] ----
  if (tid < 16 * NP) {
    int r = tid / NP, pp = tid - r * NP;
    const float* zr = z2 + r * 132;
    float a0 = b3[pp], a1 = 0.f, a2 = 0.f, a3 = 0.f;
    #pragma unroll 8
    for (int k = 0; k < 128; k += 4) {
      float4 f = *(const float4*)(zr + k);
      a0 = fmaf(f.x, W3[k * NP + pp],       a0);
      a1 = fmaf(f.y, W3[(k + 1) * NP + pp], a1);
      a2 = fmaf(f.z, W3[(k + 2) * NP + pp], a2);
      a3 = fmaf(f.w, W3[(k + 3) * NP + pp], a3);
    }
    float a = (a0 + a1) + (a2 + a3);
    int row = r0 + r;
    int bb = row >> 11, nn = row & 2047;
    out[(size_t)bb * (NP * 2048) + pp * 2048 + nn] = a;
  }
}

// ---------------------------------------------------------------------------
extern "C" void kernel_launch(void* const* d_in, const int* in_sizes, int n_in,
                              void* d_out, int out_size, void* d_ws, size_t ws_size,
                              hipStream_t stream) {
  const float* x      = (const float*)d_in[0];
  const float* W_in   = (const float*)d_in[1];
  const float* b_in   = (const float*)d_in[2];
  const float* W_conv = (const float*)d_in[3];
  const float* b_conv = (const float*)d_in[4];
  const float* Wq     = (const float*)d_in[5];
  const float* bq     = (const float*)d_in[6];
  const float* Wk     = (const float*)d_in[7];
  const float* bk     = (const float*)d_in[8];  (void)bk;
  const float* Wv     = (const float*)d_in[9];
  const float* bv     = (const float*)d_in[10];
  const float* W1     = (const float*)d_in[11];
  const float* b1     = (const float*)d_in[12];
  const float* W2     = (const float*)d_in[13];
  const float* b2     = (const float*)d_in[14];
  const float* W3     = (const float*)d_in[15];
  const float* b3     = (const float*)d_in[16];
  float* ws  = (float*)d_ws;
  float* out = (float*)d_out;

  prep_kernel<<<249, 256, 0, stream>>>(W_in, b_in, W_conv, b_conv, Wk, Wv, Wq, bq, W1, W2, ws);
  attn_kernel<<<NSEQ / 2, 128, 0, stream>>>(x, bv, ws, ws + WS_CTX);
  mlp_kernel<<<NSEQ / 16, 256, 0, stream>>>(ws + WS_CTX, ws, b1, b2, W3, b3, out);
}